// Round 9
// baseline (1195.344 us; speedup 1.0000x reference)
//
#include <hip/hip_runtime.h>

#define NF 64

// bf16 helpers (round-to-nearest-even store, cheap expand load)
__device__ __forceinline__ ushort f2bf(float f) {
    uint u = __float_as_uint(f);
    u += 0x7FFFu + ((u >> 16) & 1u);
    return (ushort)(u >> 16);
}
__device__ __forceinline__ float bflo(uint u) { return __uint_as_float(u << 16); }
__device__ __forceinline__ float bfhi(uint u) { return __uint_as_float(u & 0xFFFF0000u); }

// ================= CSR build =================
__global__ void k_initcnt(int* __restrict__ cnt, int n) {
    int i = blockIdx.x * 256 + threadIdx.x;
    if (i < n) cnt[i] = 1;              // slot 0 reserved for self-loop
}

// rank[e] = arrival index of edge e within its dst bucket (>=1)
__global__ void k_rank(const int* __restrict__ dst, int* __restrict__ cnt,
                       int* __restrict__ rank, int E) {
    int e = blockIdx.x * 256 + threadIdx.x;
    if (e < E) rank[e] = atomicAdd(&cnt[dst[e]], 1);
}

// ---- exclusive scan of cnt -> rs ----
__global__ void k_scan1(const int* __restrict__ cnt, int* __restrict__ rs,
                        int* __restrict__ btot, int n) {
    __shared__ int s[256];
    int tid = threadIdx.x;
    int base = blockIdx.x * 1024;
    int v[4]; int sum = 0;
#pragma unroll
    for (int j = 0; j < 4; ++j) {
        int idx = base + tid * 4 + j;
        v[j] = (idx < n) ? cnt[idx] : 0;
        sum += v[j];
    }
    s[tid] = sum;
    __syncthreads();
    for (int off = 1; off < 256; off <<= 1) {
        int t = (tid >= off) ? s[tid - off] : 0;
        __syncthreads();
        s[tid] += t;
        __syncthreads();
    }
    int run = s[tid] - sum;
#pragma unroll
    for (int j = 0; j < 4; ++j) {
        int idx = base + tid * 4 + j;
        if (idx < n) rs[idx] = run;
        run += v[j];
    }
    if (tid == 255) btot[blockIdx.x] = s[255];
}

__global__ void k_scan2(int* __restrict__ btot, int nb) {
    if (threadIdx.x == 0) {
        int run = 0;
        for (int i = 0; i < nb; ++i) { int t = btot[i]; btot[i] = run; run += t; }
    }
}

__global__ void k_scan3(int* __restrict__ rs, const int* __restrict__ btot,
                        int n, int total) {
    int tid = threadIdx.x;
    int base = blockIdx.x * 1024;
    int off = btot[blockIdx.x];
#pragma unroll
    for (int j = 0; j < 4; ++j) {
        int idx = base + tid * 4 + j;
        if (idx < n) rs[idx] += off;
    }
    if (blockIdx.x == 0 && tid == 0) rs[n] = total;
}

// ---- fill CSR with RAW weights (no atomics) ----
__global__ void k_fill(const int* __restrict__ src, const int* __restrict__ dst,
                       const float* __restrict__ ew, const int* __restrict__ rs,
                       const int* __restrict__ rank, int2* __restrict__ csr,
                       int E, int n) {
    int e = blockIdx.x * 256 + threadIdx.x;
    int tot = E + n;
    if (e >= tot) return;
    if (e < E) {
        int d = dst[e];
        csr[rs[d] + rank[e]] = make_int2(src[e], __float_as_int(ew[e]));
    } else {
        int i = e - E;
        csr[rs[i]] = make_int2(i, __float_as_int(1.0f));   // self-loop
    }
}

// ---- deg from CSR segments (raw weights, contiguous) -> dinv ----
__global__ void k_deg(const int2* __restrict__ csr, const int* __restrict__ rs,
                      float* __restrict__ dinv, int n) {
    int i = blockIdx.x * 256 + threadIdx.x;
    if (i >= n) return;
    int beg = rs[i], end = rs[i + 1];
    float s = 0.0f;
    for (int k = beg; k < end; ++k) s += __int_as_float(csr[k].y);
    dinv[i] = rsqrtf(fmaxf(s, 1e-30f));
}

// ================= GEMM layer 1: H = dinv[row] * (x @ W), x fp32, H bf16 =================
__global__ void k_gemm1(const float* __restrict__ X, const float* __restrict__ W,
                        const float* __restrict__ dinv, ushort* __restrict__ H, int n) {
    __shared__ float Ws[64 * 64];
    __shared__ float Xs[16][64];
    int tid = threadIdx.x;
#pragma unroll
    for (int i = 0; i < 16; ++i) Ws[tid + i * 256] = W[tid + i * 256];
    int row0 = blockIdx.x * 16;
#pragma unroll
    for (int i = 0; i < 4; ++i) {
        int idx = tid + i * 256;
        int r = idx >> 6, c = idx & 63;
        int gr = row0 + r;
        Xs[r][c] = (gr < n) ? X[gr * NF + c] : 0.0f;
    }
    __syncthreads();
    int col = tid & 63;
    int rg  = tid >> 6;
    float w[64];
#pragma unroll
    for (int k = 0; k < 64; ++k) w[k] = Ws[k * 64 + col];
    float a0 = 0.f, a1 = 0.f, a2 = 0.f, a3 = 0.f;
#pragma unroll
    for (int k = 0; k < 64; ++k) {
        float wv = w[k];
        a0 += Xs[rg * 4 + 0][k] * wv;
        a1 += Xs[rg * 4 + 1][k] * wv;
        a2 += Xs[rg * 4 + 2][k] * wv;
        a3 += Xs[rg * 4 + 3][k] * wv;
    }
    int gr = row0 + rg * 4;
    if (gr + 0 < n) H[(gr + 0) * NF + col] = f2bf(dinv[gr + 0] * a0);
    if (gr + 1 < n) H[(gr + 1) * NF + col] = f2bf(dinv[gr + 1] * a1);
    if (gr + 2 < n) H[(gr + 2) * NF + col] = f2bf(dinv[gr + 2] * a2);
    if (gr + 3 < n) H[(gr + 3) * NF + col] = f2bf(dinv[gr + 3] * a3);
}

// ================= GEMM layers 2,3: H = dinv[row]*(relu(A) @ W), A bf16, H bf16 ===========
__global__ void k_gemmB(const ushort* __restrict__ A, const float* __restrict__ W,
                        const float* __restrict__ dinv, ushort* __restrict__ H, int n) {
    __shared__ float Ws[64 * 64];
    __shared__ float Xs[16][64];
    int tid = threadIdx.x;
#pragma unroll
    for (int i = 0; i < 16; ++i) Ws[tid + i * 256] = W[tid + i * 256];
    int row0 = blockIdx.x * 16;
    // stage 16 rows x 64 bf16 = 512 uints; 256 threads x 2
    const uint* Au = reinterpret_cast<const uint*>(A);
#pragma unroll
    for (int i = 0; i < 2; ++i) {
        int idx = tid + i * 256;          // uint index within tile
        int r = idx >> 5, c2 = idx & 31;  // row, uint-col (2 features)
        int gr = row0 + r;
        uint u = (gr < n) ? Au[(size_t)gr * 32 + c2] : 0u;
        Xs[r][c2 * 2 + 0] = fmaxf(bflo(u), 0.0f);
        Xs[r][c2 * 2 + 1] = fmaxf(bfhi(u), 0.0f);
    }
    __syncthreads();
    int col = tid & 63;
    int rg  = tid >> 6;
    float w[64];
#pragma unroll
    for (int k = 0; k < 64; ++k) w[k] = Ws[k * 64 + col];
    float a0 = 0.f, a1 = 0.f, a2 = 0.f, a3 = 0.f;
#pragma unroll
    for (int k = 0; k < 64; ++k) {
        float wv = w[k];
        a0 += Xs[rg * 4 + 0][k] * wv;
        a1 += Xs[rg * 4 + 1][k] * wv;
        a2 += Xs[rg * 4 + 2][k] * wv;
        a3 += Xs[rg * 4 + 3][k] * wv;
    }
    int gr = row0 + rg * 4;
    if (gr + 0 < n) H[(gr + 0) * NF + col] = f2bf(dinv[gr + 0] * a0);
    if (gr + 1 < n) H[(gr + 1) * NF + col] = f2bf(dinv[gr + 1] * a1);
    if (gr + 2 < n) H[(gr + 2) * NF + col] = f2bf(dinv[gr + 2] * a2);
    if (gr + 3 < n) H[(gr + 3) * NF + col] = f2bf(dinv[gr + 3] * a3);
}

// ================= CSR gather: out[i] = bf16( dinv[i]*sum_e ew_e*H[src_e] + b ) ==========
// wave = node; 2 groups x 32 lanes; predicated batches of 4 (no serial tail).
__global__ void k_gather(const int2* __restrict__ csr, const int* __restrict__ rs,
                         const ushort* __restrict__ H, const float* __restrict__ b,
                         const float* __restrict__ dinv, uint* __restrict__ out, int n) {
    int wid  = (blockIdx.x * 256 + threadIdx.x) >> 6;
    int lane = threadIdx.x & 63;
    if (wid >= n) return;
    int g   = lane >> 5;          // edge group 0/1
    int sub = lane & 31;          // feature-pair index
    int beg = rs[wid], end = rs[wid + 1];
    float ax = 0.f, ay = 0.f;
    for (int k = beg + g; k < end; k += 8) {
#pragma unroll
        for (int j = 0; j < 4; ++j) {
            int kk = k + 2 * j;
            bool valid = (kk < end);
            int kks = valid ? kk : beg;
            int2 p = csr[kks];
            float w = valid ? __int_as_float(p.y) : 0.0f;
            uint h = *reinterpret_cast<const uint*>(H + (size_t)p.x * NF + sub * 2);
            ax += w * bflo(h);
            ay += w * bfhi(h);
        }
    }
    ax += __shfl_xor(ax, 32);
    ay += __shfl_xor(ay, 32);
    if (g == 0) {
        float dd = dinv[wid];
        const float2* bp = reinterpret_cast<const float2*>(b);
        float2 bb = bp[sub];
        float ox = ax * dd + bb.x;
        float oy = ay * dd + bb.y;
        out[(size_t)wid * 32 + sub] = ((uint)f2bf(oy) << 16) | (uint)f2bf(ox);
    }
}

// ================= MLP head (A bf16, relu fused) + min/max =================
__global__ void k_head(const ushort* __restrict__ A, const float* __restrict__ Wm1,
                       const float* __restrict__ bm1, const float* __restrict__ Wm2,
                       const float* __restrict__ bm2, float* __restrict__ y,
                       float* __restrict__ pmn, float* __restrict__ pmx, int n) {
    __shared__ float W1s[64 * 16];
    __shared__ float b1s[16];
    __shared__ float W2s[16];
    int tid = threadIdx.x;
    for (int i = tid; i < 64 * 16; i += 256) W1s[i] = Wm1[i];
    if (tid < 16) { b1s[tid] = bm1[tid]; W2s[tid] = Wm2[tid]; }
    __syncthreads();
    int i = blockIdx.x * 256 + tid;
    float yv = 0.0f;
    bool valid = (i < n);
    if (valid) {
        float acc[16];
#pragma unroll
        for (int k = 0; k < 16; ++k) acc[k] = b1s[k];
        const uint4* row = reinterpret_cast<const uint4*>(A + (size_t)i * NF);
#pragma unroll
        for (int jj = 0; jj < 8; ++jj) {
            uint4 u4 = row[jj];
            float hv;
            hv = fmaxf(bflo(u4.x), 0.f);
#pragma unroll
            for (int k = 0; k < 16; ++k) acc[k] += hv * W1s[(jj * 8 + 0) * 16 + k];
            hv = fmaxf(bfhi(u4.x), 0.f);
#pragma unroll
            for (int k = 0; k < 16; ++k) acc[k] += hv * W1s[(jj * 8 + 1) * 16 + k];
            hv = fmaxf(bflo(u4.y), 0.f);
#pragma unroll
            for (int k = 0; k < 16; ++k) acc[k] += hv * W1s[(jj * 8 + 2) * 16 + k];
            hv = fmaxf(bfhi(u4.y), 0.f);
#pragma unroll
            for (int k = 0; k < 16; ++k) acc[k] += hv * W1s[(jj * 8 + 3) * 16 + k];
            hv = fmaxf(bflo(u4.z), 0.f);
#pragma unroll
            for (int k = 0; k < 16; ++k) acc[k] += hv * W1s[(jj * 8 + 4) * 16 + k];
            hv = fmaxf(bfhi(u4.z), 0.f);
#pragma unroll
            for (int k = 0; k < 16; ++k) acc[k] += hv * W1s[(jj * 8 + 5) * 16 + k];
            hv = fmaxf(bflo(u4.w), 0.f);
#pragma unroll
            for (int k = 0; k < 16; ++k) acc[k] += hv * W1s[(jj * 8 + 6) * 16 + k];
            hv = fmaxf(bfhi(u4.w), 0.f);
#pragma unroll
            for (int k = 0; k < 16; ++k) acc[k] += hv * W1s[(jj * 8 + 7) * 16 + k];
        }
        yv = bm2[0];
#pragma unroll
        for (int k = 0; k < 16; ++k) yv += fmaxf(acc[k], 0.f) * W2s[k];
        y[i] = yv;
    }
    __shared__ float smn[256], smx[256];
    smn[tid] = valid ? yv : 1e30f;
    smx[tid] = valid ? yv : -1e30f;
    __syncthreads();
    for (int s = 128; s > 0; s >>= 1) {
        if (tid < s) {
            smn[tid] = fminf(smn[tid], smn[tid + s]);
            smx[tid] = fmaxf(smx[tid], smx[tid + s]);
        }
        __syncthreads();
    }
    if (tid == 0) { pmn[blockIdx.x] = smn[0]; pmx[blockIdx.x] = smx[0]; }
}

__global__ void k_minmax(const float* __restrict__ pmn, const float* __restrict__ pmx,
                         float* __restrict__ mm, int nb) {
    __shared__ float smn[512], smx[512];
    int tid = threadIdx.x;
    float mn = 1e30f, mx = -1e30f;
    for (int i = tid; i < nb; i += 512) {
        mn = fminf(mn, pmn[i]);
        mx = fmaxf(mx, pmx[i]);
    }
    smn[tid] = mn; smx[tid] = mx;
    __syncthreads();
    for (int s = 256; s > 0; s >>= 1) {
        if (tid < s) {
            smn[tid] = fminf(smn[tid], smn[tid + s]);
            smx[tid] = fmaxf(smx[tid], smx[tid + s]);
        }
        __syncthreads();
    }
    if (tid == 0) { mm[0] = smn[0]; mm[1] = smx[0]; }
}

__global__ void k_nrm(const float* __restrict__ y, const float* __restrict__ mm,
                      float* __restrict__ out, int n) {
    int i = blockIdx.x * 256 + threadIdx.x;
    if (i >= n) return;
    float mn = mm[0], mx = mm[1];
    out[i] = (y[i] - mn) / (mx - mn);
}

// ================= launch =================
extern "C" void kernel_launch(void* const* d_in, const int* in_sizes, int n_in,
                              void* d_out, int out_size, void* d_ws, size_t ws_size,
                              hipStream_t stream) {
    const float* x   = (const float*)d_in[0];
    const int*   ei  = (const int*)d_in[1];
    const float* ep  = (const float*)d_in[2];
    const float* W1  = (const float*)d_in[3];
    const float* b1  = (const float*)d_in[4];
    const float* W2  = (const float*)d_in[5];
    const float* b2  = (const float*)d_in[6];
    const float* W3  = (const float*)d_in[7];
    const float* b3  = (const float*)d_in[8];
    const float* Wm1 = (const float*)d_in[9];
    const float* bm1 = (const float*)d_in[10];
    const float* Wm2 = (const float*)d_in[11];
    const float* bm2 = (const float*)d_in[12];

    const int n = in_sizes[0] / NF;   // 100000
    const int E = in_sizes[2];        // 1600000
    const int* srcv = ei;
    const int* dstv = ei + E;
    const int tot = E + n;

    float* ws = (float*)d_ws;
    size_t pos = 0;
    auto alloc = [&](size_t cnt) {
        float* p = ws + pos;
        pos += (cnt + 255) & ~(size_t)255;
        return p;
    };
    float*  dinv = alloc(n);
    int*    cnt  = (int*)alloc(n);
    int*    rs   = (int*)alloc(n + 1);
    int*    rank = (int*)alloc(E);
    int*    btot = (int*)alloc(1024);
    int2*   csr  = (int2*)alloc((size_t)tot * 2);
    float*  y    = alloc(n);
    float*  pmn  = alloc(1024);
    float*  pmx  = alloc(1024);
    float*  mm   = alloc(2);
    ushort* bufA = (ushort*)alloc((size_t)n * NF / 2); // bf16 agg
    ushort* bufH = (ushort*)alloc((size_t)n * NF / 2); // bf16 H (dinv-scaled)

    const int TPB = 256;
    int gn  = (n + TPB - 1) / TPB;
    int gE  = (E + TPB - 1) / TPB;
    int gT  = (tot + TPB - 1) / TPB;
    int gG  = (n + 15) / 16;
    int gW  = (n * 64 + TPB - 1) / TPB;     // gather: 4 nodes/block
    int gH  = (n + TPB - 1) / TPB;
    int nb  = (n + 1023) / 1024;            // scan blocks

    // ---- CSR build (raw weights; dinv folded into gemm/gather epilogues) ----
    k_initcnt<<<gn, TPB, 0, stream>>>(cnt, n);
    k_rank<<<gE, TPB, 0, stream>>>(dstv, cnt, rank, E);
    k_scan1<<<nb, TPB, 0, stream>>>(cnt, rs, btot, n);
    k_scan2<<<1, 64, 0, stream>>>(btot, nb);
    k_scan3<<<nb, TPB, 0, stream>>>(rs, btot, n, tot);
    k_fill<<<gT, TPB, 0, stream>>>(srcv, dstv, ep, rs, rank, csr, E, n);
    k_deg<<<gn, TPB, 0, stream>>>(csr, rs, dinv, n);

    // ---- layer 1 ----
    k_gemm1<<<gG, TPB, 0, stream>>>(x, W1, dinv, bufH, n);
    k_gather<<<gW, TPB, 0, stream>>>(csr, rs, bufH, b1, dinv, (uint*)bufA, n);
    // ---- layer 2 ----
    k_gemmB<<<gG, TPB, 0, stream>>>(bufA, W2, dinv, bufH, n);
    k_gather<<<gW, TPB, 0, stream>>>(csr, rs, bufH, b2, dinv, (uint*)bufA, n);
    // ---- layer 3 ----
    k_gemmB<<<gG, TPB, 0, stream>>>(bufA, W3, dinv, bufH, n);
    k_gather<<<gW, TPB, 0, stream>>>(csr, rs, bufH, b3, dinv, (uint*)bufA, n);

    // ---- head + minmax + normalize ----
    k_head<<<gH, TPB, 0, stream>>>(bufA, Wm1, bm1, Wm2, bm2, y, pmn, pmx, n);
    k_minmax<<<1, 512, 0, stream>>>(pmn, pmx, mm, gH);
    k_nrm<<<gn, TPB, 0, stream>>>(y, mm, (float*)d_out, n);
}

// Round 10
// 557.558 us; speedup vs baseline: 2.1439x; 2.1439x over previous
//
#include <hip/hip_runtime.h>

#define NF 64

// bf16 helpers (round-to-nearest-even store, cheap expand load)
__device__ __forceinline__ ushort f2bf(float f) {
    uint u = __float_as_uint(f);
    u += 0x7FFFu + ((u >> 16) & 1u);
    return (ushort)(u >> 16);
}
__device__ __forceinline__ float bflo(uint u) { return __uint_as_float(u << 16); }
__device__ __forceinline__ float bfhi(uint u) { return __uint_as_float(u & 0xFFFF0000u); }

// ================= CSR build =================
__global__ void k_initcnt(int* __restrict__ cnt, int n) {
    int i = blockIdx.x * 256 + threadIdx.x;
    if (i < n) cnt[i] = 1;              // slot 0 reserved for self-loop
}

// rank[e] = arrival index of edge e within its dst bucket (>=1)
__global__ void k_rank(const int* __restrict__ dst, int* __restrict__ cnt,
                       int* __restrict__ rank, int E) {
    int e = blockIdx.x * 256 + threadIdx.x;
    if (e < E) rank[e] = atomicAdd(&cnt[dst[e]], 1);
}

// ---- exclusive scan of cnt -> rs ----
__global__ void k_scan1(const int* __restrict__ cnt, int* __restrict__ rs,
                        int* __restrict__ btot, int n) {
    __shared__ int s[256];
    int tid = threadIdx.x;
    int base = blockIdx.x * 1024;
    int v[4]; int sum = 0;
#pragma unroll
    for (int j = 0; j < 4; ++j) {
        int idx = base + tid * 4 + j;
        v[j] = (idx < n) ? cnt[idx] : 0;
        sum += v[j];
    }
    s[tid] = sum;
    __syncthreads();
    for (int off = 1; off < 256; off <<= 1) {
        int t = (tid >= off) ? s[tid - off] : 0;
        __syncthreads();
        s[tid] += t;
        __syncthreads();
    }
    int run = s[tid] - sum;
#pragma unroll
    for (int j = 0; j < 4; ++j) {
        int idx = base + tid * 4 + j;
        if (idx < n) rs[idx] = run;
        run += v[j];
    }
    if (tid == 255) btot[blockIdx.x] = s[255];
}

__global__ void k_scan2(int* __restrict__ btot, int nb) {
    if (threadIdx.x == 0) {
        int run = 0;
        for (int i = 0; i < nb; ++i) { int t = btot[i]; btot[i] = run; run += t; }
    }
}

__global__ void k_scan3(int* __restrict__ rs, const int* __restrict__ btot,
                        int n, int total) {
    int tid = threadIdx.x;
    int base = blockIdx.x * 1024;
    int off = btot[blockIdx.x];
#pragma unroll
    for (int j = 0; j < 4; ++j) {
        int idx = base + tid * 4 + j;
        if (idx < n) rs[idx] += off;
    }
    if (blockIdx.x == 0 && tid == 0) rs[n] = total;
}

// ---- fill CSR with RAW weights (no atomics) ----
__global__ void k_fill(const int* __restrict__ src, const int* __restrict__ dst,
                       const float* __restrict__ ew, const int* __restrict__ rs,
                       const int* __restrict__ rank, int2* __restrict__ csr,
                       int E, int n) {
    int e = blockIdx.x * 256 + threadIdx.x;
    int tot = E + n;
    if (e >= tot) return;
    if (e < E) {
        int d = dst[e];
        csr[rs[d] + rank[e]] = make_int2(src[e], __float_as_int(ew[e]));
    } else {
        int i = e - E;
        csr[rs[i]] = make_int2(i, __float_as_int(1.0f));   // self-loop
    }
}

// ---- deg from CSR segments (raw weights, contiguous) -> dinv ----
__global__ void k_deg(const int2* __restrict__ csr, const int* __restrict__ rs,
                      float* __restrict__ dinv, int n) {
    int i = blockIdx.x * 256 + threadIdx.x;
    if (i >= n) return;
    int beg = rs[i], end = rs[i + 1];
    float s = 0.0f;
    for (int k = beg; k < end; ++k) s += __int_as_float(csr[k].y);
    dinv[i] = rsqrtf(fmaxf(s, 1e-30f));
}

// ================= GEMM layer 1: H = dinv[row] * (x @ W), x fp32, H bf16 =================
// __launch_bounds__(256,2): VGPR budget 256 so the w[64] register cache does
// NOT spill (r9: compiler capped at 64 VGPR -> 1.4 GB scratch traffic, 350 us).
__global__ __launch_bounds__(256, 2)
void k_gemm1(const float* __restrict__ X, const float* __restrict__ W,
             const float* __restrict__ dinv, ushort* __restrict__ H, int n) {
    __shared__ float Ws[64 * 64];
    __shared__ float Xs[16][64];
    int tid = threadIdx.x;
#pragma unroll
    for (int i = 0; i < 16; ++i) Ws[tid + i * 256] = W[tid + i * 256];
    int row0 = blockIdx.x * 16;
#pragma unroll
    for (int i = 0; i < 4; ++i) {
        int idx = tid + i * 256;
        int r = idx >> 6, c = idx & 63;
        int gr = row0 + r;
        Xs[r][c] = (gr < n) ? X[gr * NF + c] : 0.0f;
    }
    __syncthreads();
    int col = tid & 63;
    int rg  = tid >> 6;
    float w[64];
#pragma unroll
    for (int k = 0; k < 64; ++k) w[k] = Ws[k * 64 + col];
    float a0 = 0.f, a1 = 0.f, a2 = 0.f, a3 = 0.f;
#pragma unroll
    for (int k = 0; k < 64; ++k) {
        float wv = w[k];
        a0 += Xs[rg * 4 + 0][k] * wv;
        a1 += Xs[rg * 4 + 1][k] * wv;
        a2 += Xs[rg * 4 + 2][k] * wv;
        a3 += Xs[rg * 4 + 3][k] * wv;
    }
    int gr = row0 + rg * 4;
    if (gr + 0 < n) H[(gr + 0) * NF + col] = f2bf(dinv[gr + 0] * a0);
    if (gr + 1 < n) H[(gr + 1) * NF + col] = f2bf(dinv[gr + 1] * a1);
    if (gr + 2 < n) H[(gr + 2) * NF + col] = f2bf(dinv[gr + 2] * a2);
    if (gr + 3 < n) H[(gr + 3) * NF + col] = f2bf(dinv[gr + 3] * a3);
}

// ================= GEMM layers 2,3: H = dinv[row]*(relu(A) @ W), A bf16, H bf16 ===========
__global__ __launch_bounds__(256, 2)
void k_gemmB(const ushort* __restrict__ A, const float* __restrict__ W,
             const float* __restrict__ dinv, ushort* __restrict__ H, int n) {
    __shared__ float Ws[64 * 64];
    __shared__ float Xs[16][64];
    int tid = threadIdx.x;
#pragma unroll
    for (int i = 0; i < 16; ++i) Ws[tid + i * 256] = W[tid + i * 256];
    int row0 = blockIdx.x * 16;
    // stage 16 rows x 64 bf16 = 512 uints; 256 threads x 2
    const uint* Au = reinterpret_cast<const uint*>(A);
#pragma unroll
    for (int i = 0; i < 2; ++i) {
        int idx = tid + i * 256;          // uint index within tile
        int r = idx >> 5, c2 = idx & 31;  // row, uint-col (2 features)
        int gr = row0 + r;
        uint u = (gr < n) ? Au[(size_t)gr * 32 + c2] : 0u;
        Xs[r][c2 * 2 + 0] = fmaxf(bflo(u), 0.0f);
        Xs[r][c2 * 2 + 1] = fmaxf(bfhi(u), 0.0f);
    }
    __syncthreads();
    int col = tid & 63;
    int rg  = tid >> 6;
    float w[64];
#pragma unroll
    for (int k = 0; k < 64; ++k) w[k] = Ws[k * 64 + col];
    float a0 = 0.f, a1 = 0.f, a2 = 0.f, a3 = 0.f;
#pragma unroll
    for (int k = 0; k < 64; ++k) {
        float wv = w[k];
        a0 += Xs[rg * 4 + 0][k] * wv;
        a1 += Xs[rg * 4 + 1][k] * wv;
        a2 += Xs[rg * 4 + 2][k] * wv;
        a3 += Xs[rg * 4 + 3][k] * wv;
    }
    int gr = row0 + rg * 4;
    if (gr + 0 < n) H[(gr + 0) * NF + col] = f2bf(dinv[gr + 0] * a0);
    if (gr + 1 < n) H[(gr + 1) * NF + col] = f2bf(dinv[gr + 1] * a1);
    if (gr + 2 < n) H[(gr + 2) * NF + col] = f2bf(dinv[gr + 2] * a2);
    if (gr + 3 < n) H[(gr + 3) * NF + col] = f2bf(dinv[gr + 3] * a3);
}

// ================= CSR gather: out[i] = bf16( dinv[i]*sum_e ew_e*H[src_e] + b ) ==========
// wave = node; 2 groups x 32 lanes; predicated batches of 4 (no serial tail).
__global__ void k_gather(const int2* __restrict__ csr, const int* __restrict__ rs,
                         const ushort* __restrict__ H, const float* __restrict__ b,
                         const float* __restrict__ dinv, uint* __restrict__ out, int n) {
    int wid  = (blockIdx.x * 256 + threadIdx.x) >> 6;
    int lane = threadIdx.x & 63;
    if (wid >= n) return;
    int g   = lane >> 5;          // edge group 0/1
    int sub = lane & 31;          // feature-pair index
    int beg = rs[wid], end = rs[wid + 1];
    float ax = 0.f, ay = 0.f;
    for (int k = beg + g; k < end; k += 8) {
#pragma unroll
        for (int j = 0; j < 4; ++j) {
            int kk = k + 2 * j;
            bool valid = (kk < end);
            int kks = valid ? kk : beg;
            int2 p = csr[kks];
            float w = valid ? __int_as_float(p.y) : 0.0f;
            uint h = *reinterpret_cast<const uint*>(H + (size_t)p.x * NF + sub * 2);
            ax += w * bflo(h);
            ay += w * bfhi(h);
        }
    }
    ax += __shfl_xor(ax, 32);
    ay += __shfl_xor(ay, 32);
    if (g == 0) {
        float dd = dinv[wid];
        const float2* bp = reinterpret_cast<const float2*>(b);
        float2 bb = bp[sub];
        float ox = ax * dd + bb.x;
        float oy = ay * dd + bb.y;
        out[(size_t)wid * 32 + sub] = ((uint)f2bf(oy) << 16) | (uint)f2bf(ox);
    }
}

// ================= MLP head (A bf16, relu fused) + min/max =================
__global__ __launch_bounds__(256, 2)
void k_head(const ushort* __restrict__ A, const float* __restrict__ Wm1,
            const float* __restrict__ bm1, const float* __restrict__ Wm2,
            const float* __restrict__ bm2, float* __restrict__ y,
            float* __restrict__ pmn, float* __restrict__ pmx, int n) {
    __shared__ float W1s[64 * 16];
    __shared__ float b1s[16];
    __shared__ float W2s[16];
    int tid = threadIdx.x;
    for (int i = tid; i < 64 * 16; i += 256) W1s[i] = Wm1[i];
    if (tid < 16) { b1s[tid] = bm1[tid]; W2s[tid] = Wm2[tid]; }
    __syncthreads();
    int i = blockIdx.x * 256 + tid;
    float yv = 0.0f;
    bool valid = (i < n);
    if (valid) {
        float acc[16];
#pragma unroll
        for (int k = 0; k < 16; ++k) acc[k] = b1s[k];
        const uint4* row = reinterpret_cast<const uint4*>(A + (size_t)i * NF);
#pragma unroll
        for (int jj = 0; jj < 8; ++jj) {
            uint4 u4 = row[jj];
            float hv;
            hv = fmaxf(bflo(u4.x), 0.f);
#pragma unroll
            for (int k = 0; k < 16; ++k) acc[k] += hv * W1s[(jj * 8 + 0) * 16 + k];
            hv = fmaxf(bfhi(u4.x), 0.f);
#pragma unroll
            for (int k = 0; k < 16; ++k) acc[k] += hv * W1s[(jj * 8 + 1) * 16 + k];
            hv = fmaxf(bflo(u4.y), 0.f);
#pragma unroll
            for (int k = 0; k < 16; ++k) acc[k] += hv * W1s[(jj * 8 + 2) * 16 + k];
            hv = fmaxf(bfhi(u4.y), 0.f);
#pragma unroll
            for (int k = 0; k < 16; ++k) acc[k] += hv * W1s[(jj * 8 + 3) * 16 + k];
            hv = fmaxf(bflo(u4.z), 0.f);
#pragma unroll
            for (int k = 0; k < 16; ++k) acc[k] += hv * W1s[(jj * 8 + 4) * 16 + k];
            hv = fmaxf(bfhi(u4.z), 0.f);
#pragma unroll
            for (int k = 0; k < 16; ++k) acc[k] += hv * W1s[(jj * 8 + 5) * 16 + k];
            hv = fmaxf(bflo(u4.w), 0.f);
#pragma unroll
            for (int k = 0; k < 16; ++k) acc[k] += hv * W1s[(jj * 8 + 6) * 16 + k];
            hv = fmaxf(bfhi(u4.w), 0.f);
#pragma unroll
            for (int k = 0; k < 16; ++k) acc[k] += hv * W1s[(jj * 8 + 7) * 16 + k];
        }
        yv = bm2[0];
#pragma unroll
        for (int k = 0; k < 16; ++k) yv += fmaxf(acc[k], 0.f) * W2s[k];
        y[i] = yv;
    }
    __shared__ float smn[256], smx[256];
    smn[tid] = valid ? yv : 1e30f;
    smx[tid] = valid ? yv : -1e30f;
    __syncthreads();
    for (int s = 128; s > 0; s >>= 1) {
        if (tid < s) {
            smn[tid] = fminf(smn[tid], smn[tid + s]);
            smx[tid] = fmaxf(smx[tid], smx[tid + s]);
        }
        __syncthreads();
    }
    if (tid == 0) { pmn[blockIdx.x] = smn[0]; pmx[blockIdx.x] = smx[0]; }
}

__global__ void k_minmax(const float* __restrict__ pmn, const float* __restrict__ pmx,
                         float* __restrict__ mm, int nb) {
    __shared__ float smn[512], smx[512];
    int tid = threadIdx.x;
    float mn = 1e30f, mx = -1e30f;
    for (int i = tid; i < nb; i += 512) {
        mn = fminf(mn, pmn[i]);
        mx = fmaxf(mx, pmx[i]);
    }
    smn[tid] = mn; smx[tid] = mx;
    __syncthreads();
    for (int s = 256; s > 0; s >>= 1) {
        if (tid < s) {
            smn[tid] = fminf(smn[tid], smn[tid + s]);
            smx[tid] = fmaxf(smx[tid], smx[tid + s]);
        }
        __syncthreads();
    }
    if (tid == 0) { mm[0] = smn[0]; mm[1] = smx[0]; }
}

__global__ void k_nrm(const float* __restrict__ y, const float* __restrict__ mm,
                      float* __restrict__ out, int n) {
    int i = blockIdx.x * 256 + threadIdx.x;
    if (i >= n) return;
    float mn = mm[0], mx = mm[1];
    out[i] = (y[i] - mn) / (mx - mn);
}

// ================= launch =================
extern "C" void kernel_launch(void* const* d_in, const int* in_sizes, int n_in,
                              void* d_out, int out_size, void* d_ws, size_t ws_size,
                              hipStream_t stream) {
    const float* x   = (const float*)d_in[0];
    const int*   ei  = (const int*)d_in[1];
    const float* ep  = (const float*)d_in[2];
    const float* W1  = (const float*)d_in[3];
    const float* b1  = (const float*)d_in[4];
    const float* W2  = (const float*)d_in[5];
    const float* b2  = (const float*)d_in[6];
    const float* W3  = (const float*)d_in[7];
    const float* b3  = (const float*)d_in[8];
    const float* Wm1 = (const float*)d_in[9];
    const float* bm1 = (const float*)d_in[10];
    const float* Wm2 = (const float*)d_in[11];
    const float* bm2 = (const float*)d_in[12];

    const int n = in_sizes[0] / NF;   // 100000
    const int E = in_sizes[2];        // 1600000
    const int* srcv = ei;
    const int* dstv = ei + E;
    const int tot = E + n;

    float* ws = (float*)d_ws;
    size_t pos = 0;
    auto alloc = [&](size_t cnt) {
        float* p = ws + pos;
        pos += (cnt + 255) & ~(size_t)255;
        return p;
    };
    float*  dinv = alloc(n);
    int*    cnt  = (int*)alloc(n);
    int*    rs   = (int*)alloc(n + 1);
    int*    rank = (int*)alloc(E);
    int*    btot = (int*)alloc(1024);
    int2*   csr  = (int2*)alloc((size_t)tot * 2);
    float*  y    = alloc(n);
    float*  pmn  = alloc(1024);
    float*  pmx  = alloc(1024);
    float*  mm   = alloc(2);
    ushort* bufA = (ushort*)alloc((size_t)n * NF / 2); // bf16 agg
    ushort* bufH = (ushort*)alloc((size_t)n * NF / 2); // bf16 H (dinv-scaled)

    const int TPB = 256;
    int gn  = (n + TPB - 1) / TPB;
    int gE  = (E + TPB - 1) / TPB;
    int gT  = (tot + TPB - 1) / TPB;
    int gG  = (n + 15) / 16;
    int gW  = (n * 64 + TPB - 1) / TPB;     // gather: 4 nodes/block
    int gH  = (n + TPB - 1) / TPB;
    int nb  = (n + 1023) / 1024;            // scan blocks

    // ---- CSR build (raw weights; dinv folded into gemm/gather epilogues) ----
    k_initcnt<<<gn, TPB, 0, stream>>>(cnt, n);
    k_rank<<<gE, TPB, 0, stream>>>(dstv, cnt, rank, E);
    k_scan1<<<nb, TPB, 0, stream>>>(cnt, rs, btot, n);
    k_scan2<<<1, 64, 0, stream>>>(btot, nb);
    k_scan3<<<nb, TPB, 0, stream>>>(rs, btot, n, tot);
    k_fill<<<gT, TPB, 0, stream>>>(srcv, dstv, ep, rs, rank, csr, E, n);
    k_deg<<<gn, TPB, 0, stream>>>(csr, rs, dinv, n);

    // ---- layer 1 ----
    k_gemm1<<<gG, TPB, 0, stream>>>(x, W1, dinv, bufH, n);
    k_gather<<<gW, TPB, 0, stream>>>(csr, rs, bufH, b1, dinv, (uint*)bufA, n);
    // ---- layer 2 ----
    k_gemmB<<<gG, TPB, 0, stream>>>(bufA, W2, dinv, bufH, n);
    k_gather<<<gW, TPB, 0, stream>>>(csr, rs, bufH, b2, dinv, (uint*)bufA, n);
    // ---- layer 3 ----
    k_gemmB<<<gG, TPB, 0, stream>>>(bufA, W3, dinv, bufH, n);
    k_gather<<<gW, TPB, 0, stream>>>(csr, rs, bufH, b3, dinv, (uint*)bufA, n);

    // ---- head + minmax + normalize ----
    k_head<<<gH, TPB, 0, stream>>>(bufA, Wm1, bm1, Wm2, bm2, y, pmn, pmx, n);
    k_minmax<<<1, 512, 0, stream>>>(pmn, pmx, mm, gH);
    k_nrm<<<gn, TPB, 0, stream>>>(y, mm, (float*)d_out, n);
}

// Round 11
// 441.515 us; speedup vs baseline: 2.7074x; 1.2628x over previous
//
#include <hip/hip_runtime.h>

#define NF 64

// bf16 helpers (round-to-nearest-even store, cheap expand load)
__device__ __forceinline__ ushort f2bf(float f) {
    uint u = __float_as_uint(f);
    u += 0x7FFFu + ((u >> 16) & 1u);
    return (ushort)(u >> 16);
}
__device__ __forceinline__ float bflo(uint u) { return __uint_as_float(u << 16); }
__device__ __forceinline__ float bfhi(uint u) { return __uint_as_float(u & 0xFFFF0000u); }

// ================= CSR build =================
__global__ void k_initcnt(int* __restrict__ cnt, int n) {
    int i = blockIdx.x * 256 + threadIdx.x;
    if (i < n) cnt[i] = 1;              // slot 0 reserved for self-loop
}

// rank[e] = arrival index of edge e within its dst bucket (>=1)
__global__ void k_rank(const int* __restrict__ dst, int* __restrict__ cnt,
                       int* __restrict__ rank, int E) {
    int e = blockIdx.x * 256 + threadIdx.x;
    if (e < E) rank[e] = atomicAdd(&cnt[dst[e]], 1);
}

// ---- exclusive scan of cnt -> rs ----
__global__ void k_scan1(const int* __restrict__ cnt, int* __restrict__ rs,
                        int* __restrict__ btot, int n) {
    __shared__ int s[256];
    int tid = threadIdx.x;
    int base = blockIdx.x * 1024;
    int v[4]; int sum = 0;
#pragma unroll
    for (int j = 0; j < 4; ++j) {
        int idx = base + tid * 4 + j;
        v[j] = (idx < n) ? cnt[idx] : 0;
        sum += v[j];
    }
    s[tid] = sum;
    __syncthreads();
    for (int off = 1; off < 256; off <<= 1) {
        int t = (tid >= off) ? s[tid - off] : 0;
        __syncthreads();
        s[tid] += t;
        __syncthreads();
    }
    int run = s[tid] - sum;
#pragma unroll
    for (int j = 0; j < 4; ++j) {
        int idx = base + tid * 4 + j;
        if (idx < n) rs[idx] = run;
        run += v[j];
    }
    if (tid == 255) btot[blockIdx.x] = s[255];
}

__global__ void k_scan2(int* __restrict__ btot, int nb) {
    if (threadIdx.x == 0) {
        int run = 0;
        for (int i = 0; i < nb; ++i) { int t = btot[i]; btot[i] = run; run += t; }
    }
}

__global__ void k_scan3(int* __restrict__ rs, const int* __restrict__ btot,
                        int n, int total) {
    int tid = threadIdx.x;
    int base = blockIdx.x * 1024;
    int off = btot[blockIdx.x];
#pragma unroll
    for (int j = 0; j < 4; ++j) {
        int idx = base + tid * 4 + j;
        if (idx < n) rs[idx] += off;
    }
    if (blockIdx.x == 0 && tid == 0) rs[n] = total;
}

// ---- fill CSR with RAW weights (no atomics) ----
__global__ void k_fill(const int* __restrict__ src, const int* __restrict__ dst,
                       const float* __restrict__ ew, const int* __restrict__ rs,
                       const int* __restrict__ rank, int2* __restrict__ csr,
                       int E, int n) {
    int e = blockIdx.x * 256 + threadIdx.x;
    int tot = E + n;
    if (e >= tot) return;
    if (e < E) {
        int d = dst[e];
        csr[rs[d] + rank[e]] = make_int2(src[e], __float_as_int(ew[e]));
    } else {
        int i = e - E;
        csr[rs[i]] = make_int2(i, __float_as_int(1.0f));   // self-loop
    }
}

// ---- deg from CSR segments (raw weights, contiguous) -> dinv ----
__global__ void k_deg(const int2* __restrict__ csr, const int* __restrict__ rs,
                      float* __restrict__ dinv, int n) {
    int i = blockIdx.x * 256 + threadIdx.x;
    if (i >= n) return;
    int beg = rs[i], end = rs[i + 1];
    float s = 0.0f;
    for (int k = beg; k < end; ++k) s += __int_as_float(csr[k].y);
    dinv[i] = rsqrtf(fmaxf(s, 1e-30f));
}

// ================= GEMM layer 1: H = dinv[row] * (x @ W), x fp32, H bf16 =================
// K-loop chunked by 8 (#pragma unroll 1 outer): max 8 live w-values -> no
// register-array spill regardless of compiler heuristics (r9/r10 lesson:
// float w[64] cache spilled at VGPR=64 AND VGPR=128, 90-400 MB scratch traffic).
// Ws[k*64+col] is stride-1 across the wave (2 lanes/bank = conflict-free);
// Xs[.][k] is a wave-broadcast.
__global__ void k_gemm1(const float* __restrict__ X, const float* __restrict__ W,
                        const float* __restrict__ dinv, ushort* __restrict__ H, int n) {
    __shared__ float Ws[64 * 64];
    __shared__ float Xs[16][64];
    int tid = threadIdx.x;
#pragma unroll
    for (int i = 0; i < 16; ++i) Ws[tid + i * 256] = W[tid + i * 256];
    int row0 = blockIdx.x * 16;
#pragma unroll
    for (int i = 0; i < 4; ++i) {
        int idx = tid + i * 256;
        int r = idx >> 6, c = idx & 63;
        int gr = row0 + r;
        Xs[r][c] = (gr < n) ? X[gr * NF + c] : 0.0f;
    }
    __syncthreads();
    int col = tid & 63;
    int rg  = tid >> 6;
    float a0 = 0.f, a1 = 0.f, a2 = 0.f, a3 = 0.f;
#pragma unroll 1
    for (int kb = 0; kb < 64; kb += 8) {
#pragma unroll
        for (int j = 0; j < 8; ++j) {
            int k = kb + j;
            float wv = Ws[k * 64 + col];
            a0 += Xs[rg * 4 + 0][k] * wv;
            a1 += Xs[rg * 4 + 1][k] * wv;
            a2 += Xs[rg * 4 + 2][k] * wv;
            a3 += Xs[rg * 4 + 3][k] * wv;
        }
    }
    int gr = row0 + rg * 4;
    if (gr + 0 < n) H[(gr + 0) * NF + col] = f2bf(dinv[gr + 0] * a0);
    if (gr + 1 < n) H[(gr + 1) * NF + col] = f2bf(dinv[gr + 1] * a1);
    if (gr + 2 < n) H[(gr + 2) * NF + col] = f2bf(dinv[gr + 2] * a2);
    if (gr + 3 < n) H[(gr + 3) * NF + col] = f2bf(dinv[gr + 3] * a3);
}

// ================= GEMM layers 2,3: H = dinv[row]*(relu(A) @ W), A bf16, H bf16 ===========
__global__ void k_gemmB(const ushort* __restrict__ A, const float* __restrict__ W,
                        const float* __restrict__ dinv, ushort* __restrict__ H, int n) {
    __shared__ float Ws[64 * 64];
    __shared__ float Xs[16][64];
    int tid = threadIdx.x;
#pragma unroll
    for (int i = 0; i < 16; ++i) Ws[tid + i * 256] = W[tid + i * 256];
    int row0 = blockIdx.x * 16;
    // stage 16 rows x 64 bf16 = 512 uints; 256 threads x 2; relu fused
    const uint* Au = reinterpret_cast<const uint*>(A);
#pragma unroll
    for (int i = 0; i < 2; ++i) {
        int idx = tid + i * 256;          // uint index within tile
        int r = idx >> 5, c2 = idx & 31;  // row, uint-col (2 features)
        int gr = row0 + r;
        uint u = (gr < n) ? Au[(size_t)gr * 32 + c2] : 0u;
        Xs[r][c2 * 2 + 0] = fmaxf(bflo(u), 0.0f);
        Xs[r][c2 * 2 + 1] = fmaxf(bfhi(u), 0.0f);
    }
    __syncthreads();
    int col = tid & 63;
    int rg  = tid >> 6;
    float a0 = 0.f, a1 = 0.f, a2 = 0.f, a3 = 0.f;
#pragma unroll 1
    for (int kb = 0; kb < 64; kb += 8) {
#pragma unroll
        for (int j = 0; j < 8; ++j) {
            int k = kb + j;
            float wv = Ws[k * 64 + col];
            a0 += Xs[rg * 4 + 0][k] * wv;
            a1 += Xs[rg * 4 + 1][k] * wv;
            a2 += Xs[rg * 4 + 2][k] * wv;
            a3 += Xs[rg * 4 + 3][k] * wv;
        }
    }
    int gr = row0 + rg * 4;
    if (gr + 0 < n) H[(gr + 0) * NF + col] = f2bf(dinv[gr + 0] * a0);
    if (gr + 1 < n) H[(gr + 1) * NF + col] = f2bf(dinv[gr + 1] * a1);
    if (gr + 2 < n) H[(gr + 2) * NF + col] = f2bf(dinv[gr + 2] * a2);
    if (gr + 3 < n) H[(gr + 3) * NF + col] = f2bf(dinv[gr + 3] * a3);
}

// ================= CSR gather: out[i] = bf16( dinv[i]*sum_e ew_e*H[src_e] + b ) ==========
// wave = node; 2 groups x 32 lanes; predicated batches of 4 (no serial tail).
__global__ void k_gather(const int2* __restrict__ csr, const int* __restrict__ rs,
                         const ushort* __restrict__ H, const float* __restrict__ b,
                         const float* __restrict__ dinv, uint* __restrict__ out, int n) {
    int wid  = (blockIdx.x * 256 + threadIdx.x) >> 6;
    int lane = threadIdx.x & 63;
    if (wid >= n) return;
    int g   = lane >> 5;          // edge group 0/1
    int sub = lane & 31;          // feature-pair index
    int beg = rs[wid], end = rs[wid + 1];
    float ax = 0.f, ay = 0.f;
    for (int k = beg + g; k < end; k += 8) {
#pragma unroll
        for (int j = 0; j < 4; ++j) {
            int kk = k + 2 * j;
            bool valid = (kk < end);
            int kks = valid ? kk : beg;
            int2 p = csr[kks];
            float w = valid ? __int_as_float(p.y) : 0.0f;
            uint h = *reinterpret_cast<const uint*>(H + (size_t)p.x * NF + sub * 2);
            ax += w * bflo(h);
            ay += w * bfhi(h);
        }
    }
    ax += __shfl_xor(ax, 32);
    ay += __shfl_xor(ay, 32);
    if (g == 0) {
        float dd = dinv[wid];
        const float2* bp = reinterpret_cast<const float2*>(b);
        float2 bb = bp[sub];
        float ox = ax * dd + bb.x;
        float oy = ay * dd + bb.y;
        out[(size_t)wid * 32 + sub] = ((uint)f2bf(oy) << 16) | (uint)f2bf(ox);
    }
}

// ================= MLP head (A bf16, relu fused) + min/max =================
__global__ void k_head(const ushort* __restrict__ A, const float* __restrict__ Wm1,
                       const float* __restrict__ bm1, const float* __restrict__ Wm2,
                       const float* __restrict__ bm2, float* __restrict__ y,
                       float* __restrict__ pmn, float* __restrict__ pmx, int n) {
    __shared__ float W1s[64 * 16];
    __shared__ float b1s[16];
    __shared__ float W2s[16];
    int tid = threadIdx.x;
    for (int i = tid; i < 64 * 16; i += 256) W1s[i] = Wm1[i];
    if (tid < 16) { b1s[tid] = bm1[tid]; W2s[tid] = Wm2[tid]; }
    __syncthreads();
    int i = blockIdx.x * 256 + tid;
    float yv = 0.0f;
    bool valid = (i < n);
    if (valid) {
        float acc[16];
#pragma unroll
        for (int k = 0; k < 16; ++k) acc[k] = b1s[k];
        const uint4* row = reinterpret_cast<const uint4*>(A + (size_t)i * NF);
#pragma unroll 1
        for (int jj = 0; jj < 8; ++jj) {
            uint4 u4 = row[jj];
            float hv;
            hv = fmaxf(bflo(u4.x), 0.f);
#pragma unroll
            for (int k = 0; k < 16; ++k) acc[k] += hv * W1s[(jj * 8 + 0) * 16 + k];
            hv = fmaxf(bfhi(u4.x), 0.f);
#pragma unroll
            for (int k = 0; k < 16; ++k) acc[k] += hv * W1s[(jj * 8 + 1) * 16 + k];
            hv = fmaxf(bflo(u4.y), 0.f);
#pragma unroll
            for (int k = 0; k < 16; ++k) acc[k] += hv * W1s[(jj * 8 + 2) * 16 + k];
            hv = fmaxf(bfhi(u4.y), 0.f);
#pragma unroll
            for (int k = 0; k < 16; ++k) acc[k] += hv * W1s[(jj * 8 + 3) * 16 + k];
            hv = fmaxf(bflo(u4.z), 0.f);
#pragma unroll
            for (int k = 0; k < 16; ++k) acc[k] += hv * W1s[(jj * 8 + 4) * 16 + k];
            hv = fmaxf(bfhi(u4.z), 0.f);
#pragma unroll
            for (int k = 0; k < 16; ++k) acc[k] += hv * W1s[(jj * 8 + 5) * 16 + k];
            hv = fmaxf(bflo(u4.w), 0.f);
#pragma unroll
            for (int k = 0; k < 16; ++k) acc[k] += hv * W1s[(jj * 8 + 6) * 16 + k];
            hv = fmaxf(bfhi(u4.w), 0.f);
#pragma unroll
            for (int k = 0; k < 16; ++k) acc[k] += hv * W1s[(jj * 8 + 7) * 16 + k];
        }
        yv = bm2[0];
#pragma unroll
        for (int k = 0; k < 16; ++k) yv += fmaxf(acc[k], 0.f) * W2s[k];
        y[i] = yv;
    }
    __shared__ float smn[256], smx[256];
    smn[tid] = valid ? yv : 1e30f;
    smx[tid] = valid ? yv : -1e30f;
    __syncthreads();
    for (int s = 128; s > 0; s >>= 1) {
        if (tid < s) {
            smn[tid] = fminf(smn[tid], smn[tid + s]);
            smx[tid] = fmaxf(smx[tid], smx[tid + s]);
        }
        __syncthreads();
    }
    if (tid == 0) { pmn[blockIdx.x] = smn[0]; pmx[blockIdx.x] = smx[0]; }
}

__global__ void k_minmax(const float* __restrict__ pmn, const float* __restrict__ pmx,
                         float* __restrict__ mm, int nb) {
    __shared__ float smn[512], smx[512];
    int tid = threadIdx.x;
    float mn = 1e30f, mx = -1e30f;
    for (int i = tid; i < nb; i += 512) {
        mn = fminf(mn, pmn[i]);
        mx = fmaxf(mx, pmx[i]);
    }
    smn[tid] = mn; smx[tid] = mx;
    __syncthreads();
    for (int s = 256; s > 0; s >>= 1) {
        if (tid < s) {
            smn[tid] = fminf(smn[tid], smn[tid + s]);
            smx[tid] = fmaxf(smx[tid], smx[tid + s]);
        }
        __syncthreads();
    }
    if (tid == 0) { mm[0] = smn[0]; mm[1] = smx[0]; }
}

__global__ void k_nrm(const float* __restrict__ y, const float* __restrict__ mm,
                      float* __restrict__ out, int n) {
    int i = blockIdx.x * 256 + threadIdx.x;
    if (i >= n) return;
    float mn = mm[0], mx = mm[1];
    out[i] = (y[i] - mn) / (mx - mn);
}

// ================= launch =================
extern "C" void kernel_launch(void* const* d_in, const int* in_sizes, int n_in,
                              void* d_out, int out_size, void* d_ws, size_t ws_size,
                              hipStream_t stream) {
    const float* x   = (const float*)d_in[0];
    const int*   ei  = (const int*)d_in[1];
    const float* ep  = (const float*)d_in[2];
    const float* W1  = (const float*)d_in[3];
    const float* b1  = (const float*)d_in[4];
    const float* W2  = (const float*)d_in[5];
    const float* b2  = (const float*)d_in[6];
    const float* W3  = (const float*)d_in[7];
    const float* b3  = (const float*)d_in[8];
    const float* Wm1 = (const float*)d_in[9];
    const float* bm1 = (const float*)d_in[10];
    const float* Wm2 = (const float*)d_in[11];
    const float* bm2 = (const float*)d_in[12];

    const int n = in_sizes[0] / NF;   // 100000
    const int E = in_sizes[2];        // 1600000
    const int* srcv = ei;
    const int* dstv = ei + E;
    const int tot = E + n;

    float* ws = (float*)d_ws;
    size_t pos = 0;
    auto alloc = [&](size_t cnt) {
        float* p = ws + pos;
        pos += (cnt + 255) & ~(size_t)255;
        return p;
    };
    float*  dinv = alloc(n);
    int*    cnt  = (int*)alloc(n);
    int*    rs   = (int*)alloc(n + 1);
    int*    rank = (int*)alloc(E);
    int*    btot = (int*)alloc(1024);
    int2*   csr  = (int2*)alloc((size_t)tot * 2);
    float*  y    = alloc(n);
    float*  pmn  = alloc(1024);
    float*  pmx  = alloc(1024);
    float*  mm   = alloc(2);
    ushort* bufA = (ushort*)alloc((size_t)n * NF / 2); // bf16 agg
    ushort* bufH = (ushort*)alloc((size_t)n * NF / 2); // bf16 H (dinv-scaled)

    const int TPB = 256;
    int gn  = (n + TPB - 1) / TPB;
    int gE  = (E + TPB - 1) / TPB;
    int gT  = (tot + TPB - 1) / TPB;
    int gG  = (n + 15) / 16;
    int gW  = (n * 64 + TPB - 1) / TPB;     // gather: 4 nodes/block
    int gH  = (n + TPB - 1) / TPB;
    int nb  = (n + 1023) / 1024;            // scan blocks

    // ---- CSR build (raw weights; dinv folded into gemm/gather epilogues) ----
    k_initcnt<<<gn, TPB, 0, stream>>>(cnt, n);
    k_rank<<<gE, TPB, 0, stream>>>(dstv, cnt, rank, E);
    k_scan1<<<nb, TPB, 0, stream>>>(cnt, rs, btot, n);
    k_scan2<<<1, 64, 0, stream>>>(btot, nb);
    k_scan3<<<nb, TPB, 0, stream>>>(rs, btot, n, tot);
    k_fill<<<gT, TPB, 0, stream>>>(srcv, dstv, ep, rs, rank, csr, E, n);
    k_deg<<<gn, TPB, 0, stream>>>(csr, rs, dinv, n);

    // ---- layer 1 ----
    k_gemm1<<<gG, TPB, 0, stream>>>(x, W1, dinv, bufH, n);
    k_gather<<<gW, TPB, 0, stream>>>(csr, rs, bufH, b1, dinv, (uint*)bufA, n);
    // ---- layer 2 ----
    k_gemmB<<<gG, TPB, 0, stream>>>(bufA, W2, dinv, bufH, n);
    k_gather<<<gW, TPB, 0, stream>>>(csr, rs, bufH, b2, dinv, (uint*)bufA, n);
    // ---- layer 3 ----
    k_gemmB<<<gG, TPB, 0, stream>>>(bufA, W3, dinv, bufH, n);
    k_gather<<<gW, TPB, 0, stream>>>(csr, rs, bufH, b3, dinv, (uint*)bufA, n);

    // ---- head + minmax + normalize ----
    k_head<<<gH, TPB, 0, stream>>>(bufA, Wm1, bm1, Wm2, bm2, y, pmn, pmx, n);
    k_minmax<<<1, 512, 0, stream>>>(pmn, pmx, mm, gH);
    k_nrm<<<gn, TPB, 0, stream>>>(y, mm, (float*)d_out, n);
}

// Round 12
// 389.918 us; speedup vs baseline: 3.0656x; 1.1323x over previous
//
#include <hip/hip_runtime.h>

#define NF 64

// bf16 helpers (round-to-nearest-even store, cheap expand load)
__device__ __forceinline__ ushort f2bf(float f) {
    uint u = __float_as_uint(f);
    u += 0x7FFFu + ((u >> 16) & 1u);
    return (ushort)(u >> 16);
}
__device__ __forceinline__ float bflo(uint u) { return __uint_as_float(u << 16); }
__device__ __forceinline__ float bfhi(uint u) { return __uint_as_float(u & 0xFFFF0000u); }

// ================= CSR build =================
__global__ void k_initcnt(int* __restrict__ cnt, int n) {
    int i = blockIdx.x * 256 + threadIdx.x;
    if (i < n) cnt[i] = 1;              // slot 0 reserved for self-loop
}

// rank[e] = arrival index of edge e within its dst bucket (>=1)
__global__ void k_rank(const int* __restrict__ dst, int* __restrict__ cnt,
                       int* __restrict__ rank, int E) {
    int e = blockIdx.x * 256 + threadIdx.x;
    if (e < E) rank[e] = atomicAdd(&cnt[dst[e]], 1);
}

// ---- exclusive scan of cnt -> rs ----
__global__ void k_scan1(const int* __restrict__ cnt, int* __restrict__ rs,
                        int* __restrict__ btot, int n) {
    __shared__ int s[256];
    int tid = threadIdx.x;
    int base = blockIdx.x * 1024;
    int v[4]; int sum = 0;
#pragma unroll
    for (int j = 0; j < 4; ++j) {
        int idx = base + tid * 4 + j;
        v[j] = (idx < n) ? cnt[idx] : 0;
        sum += v[j];
    }
    s[tid] = sum;
    __syncthreads();
    for (int off = 1; off < 256; off <<= 1) {
        int t = (tid >= off) ? s[tid - off] : 0;
        __syncthreads();
        s[tid] += t;
        __syncthreads();
    }
    int run = s[tid] - sum;
#pragma unroll
    for (int j = 0; j < 4; ++j) {
        int idx = base + tid * 4 + j;
        if (idx < n) rs[idx] = run;
        run += v[j];
    }
    if (tid == 255) btot[blockIdx.x] = s[255];
}

__global__ void k_scan2(int* __restrict__ btot, int nb) {
    if (threadIdx.x == 0) {
        int run = 0;
        for (int i = 0; i < nb; ++i) { int t = btot[i]; btot[i] = run; run += t; }
    }
}

__global__ void k_scan3(int* __restrict__ rs, const int* __restrict__ btot,
                        int n, int total) {
    int tid = threadIdx.x;
    int base = blockIdx.x * 1024;
    int off = btot[blockIdx.x];
#pragma unroll
    for (int j = 0; j < 4; ++j) {
        int idx = base + tid * 4 + j;
        if (idx < n) rs[idx] += off;
    }
    if (blockIdx.x == 0 && tid == 0) rs[n] = total;
}

// ---- fill CSR with RAW weights (no atomics) ----
__global__ void k_fill(const int* __restrict__ src, const int* __restrict__ dst,
                       const float* __restrict__ ew, const int* __restrict__ rs,
                       const int* __restrict__ rank, int2* __restrict__ csr,
                       int E, int n) {
    int e = blockIdx.x * 256 + threadIdx.x;
    int tot = E + n;
    if (e >= tot) return;
    if (e < E) {
        int d = dst[e];
        csr[rs[d] + rank[e]] = make_int2(src[e], __float_as_int(ew[e]));
    } else {
        int i = e - E;
        csr[rs[i]] = make_int2(i, __float_as_int(1.0f));   // self-loop
    }
}

// ---- deg from CSR segments (raw weights, contiguous) -> dinv ----
__global__ void k_deg(const int2* __restrict__ csr, const int* __restrict__ rs,
                      float* __restrict__ dinv, int n) {
    int i = blockIdx.x * 256 + threadIdx.x;
    if (i >= n) return;
    int beg = rs[i], end = rs[i + 1];
    float s = 0.0f;
    for (int k = beg; k < end; ++k) s += __int_as_float(csr[k].y);
    dinv[i] = rsqrtf(fmaxf(s, 1e-30f));
}

// ================= GEMM layer 1: H = dinv[row] * (x @ W), x fp32, H bf16 =================
// K-loop chunked by 8 (#pragma unroll 1 outer): max 8 live w-values -> no
// register-array spill regardless of compiler heuristics (r9/r10 lesson:
// float w[64] cache spilled at VGPR=64 AND VGPR=128, 90-400 MB scratch traffic).
__global__ void k_gemm1(const float* __restrict__ X, const float* __restrict__ W,
                        const float* __restrict__ dinv, ushort* __restrict__ H, int n) {
    __shared__ float Ws[64 * 64];
    __shared__ float Xs[16][64];
    int tid = threadIdx.x;
#pragma unroll
    for (int i = 0; i < 16; ++i) Ws[tid + i * 256] = W[tid + i * 256];
    int row0 = blockIdx.x * 16;
#pragma unroll
    for (int i = 0; i < 4; ++i) {
        int idx = tid + i * 256;
        int r = idx >> 6, c = idx & 63;
        int gr = row0 + r;
        Xs[r][c] = (gr < n) ? X[gr * NF + c] : 0.0f;
    }
    __syncthreads();
    int col = tid & 63;
    int rg  = tid >> 6;
    float a0 = 0.f, a1 = 0.f, a2 = 0.f, a3 = 0.f;
#pragma unroll 1
    for (int kb = 0; kb < 64; kb += 8) {
#pragma unroll
        for (int j = 0; j < 8; ++j) {
            int k = kb + j;
            float wv = Ws[k * 64 + col];
            a0 += Xs[rg * 4 + 0][k] * wv;
            a1 += Xs[rg * 4 + 1][k] * wv;
            a2 += Xs[rg * 4 + 2][k] * wv;
            a3 += Xs[rg * 4 + 3][k] * wv;
        }
    }
    int gr = row0 + rg * 4;
    if (gr + 0 < n) H[(gr + 0) * NF + col] = f2bf(dinv[gr + 0] * a0);
    if (gr + 1 < n) H[(gr + 1) * NF + col] = f2bf(dinv[gr + 1] * a1);
    if (gr + 2 < n) H[(gr + 2) * NF + col] = f2bf(dinv[gr + 2] * a2);
    if (gr + 3 < n) H[(gr + 3) * NF + col] = f2bf(dinv[gr + 3] * a3);
}

// ================= GEMM layers 2,3: H = dinv[row]*(relu(A) @ W), A bf16, H bf16 ===========
__global__ void k_gemmB(const ushort* __restrict__ A, const float* __restrict__ W,
                        const float* __restrict__ dinv, ushort* __restrict__ H, int n) {
    __shared__ float Ws[64 * 64];
    __shared__ float Xs[16][64];
    int tid = threadIdx.x;
#pragma unroll
    for (int i = 0; i < 16; ++i) Ws[tid + i * 256] = W[tid + i * 256];
    int row0 = blockIdx.x * 16;
    // stage 16 rows x 64 bf16 = 512 uints; 256 threads x 2; relu fused
    const uint* Au = reinterpret_cast<const uint*>(A);
#pragma unroll
    for (int i = 0; i < 2; ++i) {
        int idx = tid + i * 256;          // uint index within tile
        int r = idx >> 5, c2 = idx & 31;  // row, uint-col (2 features)
        int gr = row0 + r;
        uint u = (gr < n) ? Au[(size_t)gr * 32 + c2] : 0u;
        Xs[r][c2 * 2 + 0] = fmaxf(bflo(u), 0.0f);
        Xs[r][c2 * 2 + 1] = fmaxf(bfhi(u), 0.0f);
    }
    __syncthreads();
    int col = tid & 63;
    int rg  = tid >> 6;
    float a0 = 0.f, a1 = 0.f, a2 = 0.f, a3 = 0.f;
#pragma unroll 1
    for (int kb = 0; kb < 64; kb += 8) {
#pragma unroll
        for (int j = 0; j < 8; ++j) {
            int k = kb + j;
            float wv = Ws[k * 64 + col];
            a0 += Xs[rg * 4 + 0][k] * wv;
            a1 += Xs[rg * 4 + 1][k] * wv;
            a2 += Xs[rg * 4 + 2][k] * wv;
            a3 += Xs[rg * 4 + 3][k] * wv;
        }
    }
    int gr = row0 + rg * 4;
    if (gr + 0 < n) H[(gr + 0) * NF + col] = f2bf(dinv[gr + 0] * a0);
    if (gr + 1 < n) H[(gr + 1) * NF + col] = f2bf(dinv[gr + 1] * a1);
    if (gr + 2 < n) H[(gr + 2) * NF + col] = f2bf(dinv[gr + 2] * a2);
    if (gr + 3 < n) H[(gr + 3) * NF + col] = f2bf(dinv[gr + 3] * a3);
}

// ================= CSR gather: out[i] = bf16( dinv[i]*sum_e ew_e*H[src_e] + b ) ==========
// wave = node; 2 groups x 32 lanes; r6-proven loop: unroll-4 main (k+6<end
// guard) + short stepped tail. (r11 lesson: predicated batches issue 25-40%
// extra VMEM + cndmask chains -> 76 us vs this structure's ~61.)
__global__ void k_gather(const int2* __restrict__ csr, const int* __restrict__ rs,
                         const ushort* __restrict__ H, const float* __restrict__ b,
                         const float* __restrict__ dinv, uint* __restrict__ out, int n) {
    int wid  = (blockIdx.x * 256 + threadIdx.x) >> 6;
    int lane = threadIdx.x & 63;
    if (wid >= n) return;
    int g   = lane >> 5;          // edge group 0/1
    int sub = lane & 31;          // feature-pair index
    int beg = rs[wid], end = rs[wid + 1];
    float ax = 0.f, ay = 0.f;
    int k = beg + g;
    for (; k + 6 < end; k += 8) {
        int2 p0 = csr[k + 0];
        int2 p1 = csr[k + 2];
        int2 p2 = csr[k + 4];
        int2 p3 = csr[k + 6];
        uint h0 = *reinterpret_cast<const uint*>(H + (size_t)p0.x * NF + sub * 2);
        uint h1 = *reinterpret_cast<const uint*>(H + (size_t)p1.x * NF + sub * 2);
        uint h2 = *reinterpret_cast<const uint*>(H + (size_t)p2.x * NF + sub * 2);
        uint h3 = *reinterpret_cast<const uint*>(H + (size_t)p3.x * NF + sub * 2);
        float w0 = __int_as_float(p0.y);
        float w1 = __int_as_float(p1.y);
        float w2 = __int_as_float(p2.y);
        float w3 = __int_as_float(p3.y);
        ax += w0 * bflo(h0);
        ay += w0 * bfhi(h0);
        ax += w1 * bflo(h1);
        ay += w1 * bfhi(h1);
        ax += w2 * bflo(h2);
        ay += w2 * bfhi(h2);
        ax += w3 * bflo(h3);
        ay += w3 * bfhi(h3);
    }
    for (; k < end; k += 2) {
        int2 p = csr[k];
        uint h = *reinterpret_cast<const uint*>(H + (size_t)p.x * NF + sub * 2);
        float w = __int_as_float(p.y);
        ax += w * bflo(h);
        ay += w * bfhi(h);
    }
    ax += __shfl_xor(ax, 32);
    ay += __shfl_xor(ay, 32);
    if (g == 0) {
        float dd = dinv[wid];
        const float2* bp = reinterpret_cast<const float2*>(b);
        float2 bb = bp[sub];
        float ox = ax * dd + bb.x;
        float oy = ay * dd + bb.y;
        out[(size_t)wid * 32 + sub] = ((uint)f2bf(oy) << 16) | (uint)f2bf(ox);
    }
}

// ================= MLP head (A bf16, relu fused) + min/max =================
__global__ void k_head(const ushort* __restrict__ A, const float* __restrict__ Wm1,
                       const float* __restrict__ bm1, const float* __restrict__ Wm2,
                       const float* __restrict__ bm2, float* __restrict__ y,
                       float* __restrict__ pmn, float* __restrict__ pmx, int n) {
    __shared__ float W1s[64 * 16];
    __shared__ float b1s[16];
    __shared__ float W2s[16];
    int tid = threadIdx.x;
    for (int i = tid; i < 64 * 16; i += 256) W1s[i] = Wm1[i];
    if (tid < 16) { b1s[tid] = bm1[tid]; W2s[tid] = Wm2[tid]; }
    __syncthreads();
    int i = blockIdx.x * 256 + tid;
    float yv = 0.0f;
    bool valid = (i < n);
    if (valid) {
        float acc[16];
#pragma unroll
        for (int k = 0; k < 16; ++k) acc[k] = b1s[k];
        const uint4* row = reinterpret_cast<const uint4*>(A + (size_t)i * NF);
#pragma unroll 1
        for (int jj = 0; jj < 8; ++jj) {
            uint4 u4 = row[jj];
            float hv;
            hv = fmaxf(bflo(u4.x), 0.f);
#pragma unroll
            for (int k = 0; k < 16; ++k) acc[k] += hv * W1s[(jj * 8 + 0) * 16 + k];
            hv = fmaxf(bfhi(u4.x), 0.f);
#pragma unroll
            for (int k = 0; k < 16; ++k) acc[k] += hv * W1s[(jj * 8 + 1) * 16 + k];
            hv = fmaxf(bflo(u4.y), 0.f);
#pragma unroll
            for (int k = 0; k < 16; ++k) acc[k] += hv * W1s[(jj * 8 + 2) * 16 + k];
            hv = fmaxf(bfhi(u4.y), 0.f);
#pragma unroll
            for (int k = 0; k < 16; ++k) acc[k] += hv * W1s[(jj * 8 + 3) * 16 + k];
            hv = fmaxf(bflo(u4.z), 0.f);
#pragma unroll
            for (int k = 0; k < 16; ++k) acc[k] += hv * W1s[(jj * 8 + 4) * 16 + k];
            hv = fmaxf(bfhi(u4.z), 0.f);
#pragma unroll
            for (int k = 0; k < 16; ++k) acc[k] += hv * W1s[(jj * 8 + 5) * 16 + k];
            hv = fmaxf(bflo(u4.w), 0.f);
#pragma unroll
            for (int k = 0; k < 16; ++k) acc[k] += hv * W1s[(jj * 8 + 6) * 16 + k];
            hv = fmaxf(bfhi(u4.w), 0.f);
#pragma unroll
            for (int k = 0; k < 16; ++k) acc[k] += hv * W1s[(jj * 8 + 7) * 16 + k];
        }
        yv = bm2[0];
#pragma unroll
        for (int k = 0; k < 16; ++k) yv += fmaxf(acc[k], 0.f) * W2s[k];
        y[i] = yv;
    }
    __shared__ float smn[256], smx[256];
    smn[tid] = valid ? yv : 1e30f;
    smx[tid] = valid ? yv : -1e30f;
    __syncthreads();
    for (int s = 128; s > 0; s >>= 1) {
        if (tid < s) {
            smn[tid] = fminf(smn[tid], smn[tid + s]);
            smx[tid] = fmaxf(smx[tid], smx[tid + s]);
        }
        __syncthreads();
    }
    if (tid == 0) { pmn[blockIdx.x] = smn[0]; pmx[blockIdx.x] = smx[0]; }
}

__global__ void k_minmax(const float* __restrict__ pmn, const float* __restrict__ pmx,
                         float* __restrict__ mm, int nb) {
    __shared__ float smn[512], smx[512];
    int tid = threadIdx.x;
    float mn = 1e30f, mx = -1e30f;
    for (int i = tid; i < nb; i += 512) {
        mn = fminf(mn, pmn[i]);
        mx = fmaxf(mx, pmx[i]);
    }
    smn[tid] = mn; smx[tid] = mx;
    __syncthreads();
    for (int s = 256; s > 0; s >>= 1) {
        if (tid < s) {
            smn[tid] = fminf(smn[tid], smn[tid + s]);
            smx[tid] = fmaxf(smx[tid], smx[tid + s]);
        }
        __syncthreads();
    }
    if (tid == 0) { mm[0] = smn[0]; mm[1] = smx[0]; }
}

__global__ void k_nrm(const float* __restrict__ y, const float* __restrict__ mm,
                      float* __restrict__ out, int n) {
    int i = blockIdx.x * 256 + threadIdx.x;
    if (i >= n) return;
    float mn = mm[0], mx = mm[1];
    out[i] = (y[i] - mn) / (mx - mn);
}

// ================= launch =================
extern "C" void kernel_launch(void* const* d_in, const int* in_sizes, int n_in,
                              void* d_out, int out_size, void* d_ws, size_t ws_size,
                              hipStream_t stream) {
    const float* x   = (const float*)d_in[0];
    const int*   ei  = (const int*)d_in[1];
    const float* ep  = (const float*)d_in[2];
    const float* W1  = (const float*)d_in[3];
    const float* b1  = (const float*)d_in[4];
    const float* W2  = (const float*)d_in[5];
    const float* b2  = (const float*)d_in[6];
    const float* W3  = (const float*)d_in[7];
    const float* b3  = (const float*)d_in[8];
    const float* Wm1 = (const float*)d_in[9];
    const float* bm1 = (const float*)d_in[10];
    const float* Wm2 = (const float*)d_in[11];
    const float* bm2 = (const float*)d_in[12];

    const int n = in_sizes[0] / NF;   // 100000
    const int E = in_sizes[2];        // 1600000
    const int* srcv = ei;
    const int* dstv = ei + E;
    const int tot = E + n;

    float* ws = (float*)d_ws;
    size_t pos = 0;
    auto alloc = [&](size_t cnt) {
        float* p = ws + pos;
        pos += (cnt + 255) & ~(size_t)255;
        return p;
    };
    float*  dinv = alloc(n);
    int*    cnt  = (int*)alloc(n);
    int*    rs   = (int*)alloc(n + 1);
    int*    rank = (int*)alloc(E);
    int*    btot = (int*)alloc(1024);
    int2*   csr  = (int2*)alloc((size_t)tot * 2);
    float*  y    = alloc(n);
    float*  pmn  = alloc(1024);
    float*  pmx  = alloc(1024);
    float*  mm   = alloc(2);
    ushort* bufA = (ushort*)alloc((size_t)n * NF / 2); // bf16 agg
    ushort* bufH = (ushort*)alloc((size_t)n * NF / 2); // bf16 H (dinv-scaled)

    const int TPB = 256;
    int gn  = (n + TPB - 1) / TPB;
    int gE  = (E + TPB - 1) / TPB;
    int gT  = (tot + TPB - 1) / TPB;
    int gG  = (n + 15) / 16;
    int gW  = (n * 64 + TPB - 1) / TPB;     // gather: 4 nodes/block
    int gH  = (n + TPB - 1) / TPB;
    int nb  = (n + 1023) / 1024;            // scan blocks

    // ---- CSR build (raw weights; dinv folded into gemm/gather epilogues) ----
    k_initcnt<<<gn, TPB, 0, stream>>>(cnt, n);
    k_rank<<<gE, TPB, 0, stream>>>(dstv, cnt, rank, E);
    k_scan1<<<nb, TPB, 0, stream>>>(cnt, rs, btot, n);
    k_scan2<<<1, 64, 0, stream>>>(btot, nb);
    k_scan3<<<nb, TPB, 0, stream>>>(rs, btot, n, tot);
    k_fill<<<gT, TPB, 0, stream>>>(srcv, dstv, ep, rs, rank, csr, E, n);
    k_deg<<<gn, TPB, 0, stream>>>(csr, rs, dinv, n);

    // ---- layer 1 ----
    k_gemm1<<<gG, TPB, 0, stream>>>(x, W1, dinv, bufH, n);
    k_gather<<<gW, TPB, 0, stream>>>(csr, rs, bufH, b1, dinv, (uint*)bufA, n);
    // ---- layer 2 ----
    k_gemmB<<<gG, TPB, 0, stream>>>(bufA, W2, dinv, bufH, n);
    k_gather<<<gW, TPB, 0, stream>>>(csr, rs, bufH, b2, dinv, (uint*)bufA, n);
    // ---- layer 3 ----
    k_gemmB<<<gG, TPB, 0, stream>>>(bufA, W3, dinv, bufH, n);
    k_gather<<<gW, TPB, 0, stream>>>(csr, rs, bufH, b3, dinv, (uint*)bufA, n);

    // ---- head + minmax + normalize ----
    k_head<<<gH, TPB, 0, stream>>>(bufA, Wm1, bm1, Wm2, bm2, y, pmn, pmx, n);
    k_minmax<<<1, 512, 0, stream>>>(pmn, pmx, mm, gH);
    k_nrm<<<gn, TPB, 0, stream>>>(y, mm, (float*)d_out, n);
}